// Round 3
// baseline (72.304 us; speedup 1.0000x reference)
//
#include <hip/hip_runtime.h>
#include <hip/hip_bf16.h>

typedef __bf16 bf16x8 __attribute__((ext_vector_type(8)));
typedef float  f32x4  __attribute__((ext_vector_type(4)));

#define B_SZ 1024
#define D_SZ 128
#define C_SZ 100000
#define CPAD 100096          // padded class rows (zero tail), 782*128
#define BM 128
#define BN 128
#define NG 64                // C-tile groups (grid.x)
#define NCT 782              // ceil(100000/128)

#define SCALE_F   64.0f
#define MARGIN_F  0.35f
#define CLIP_F    (1.0f - 1e-7f)
#define LOG2E_F   1.4426950408889634f
#define S_LOG2E_F (64.0f * 1.4426950408889634f)

struct bf2 { __bf16 x, y; };

__device__ __forceinline__ void gload_lds16(const void* g, void* l) {
    __builtin_amdgcn_global_load_lds(
        (const __attribute__((address_space(1))) void*)g,
        (__attribute__((address_space(3))) void*)l, 16, 0, 0);
}

// ---- Kernel A: L2-normalize W rows -> bf16 (+zero pad rows) + convert E -> bf16
__global__ void norm_conv(const float* __restrict__ W, __bf16* __restrict__ Wb,
                          const float* __restrict__ E, __bf16* __restrict__ Eb) {
    const int b = blockIdx.x;
    if (b < 25024) {
        const int row  = b * 4 + (threadIdx.x >> 6);
        const int lane = threadIdx.x & 63;
        if (row < C_SZ) {
            float2 v = reinterpret_cast<const float2*>(W + (size_t)row * D_SZ)[lane];
            float ss = v.x * v.x + v.y * v.y;
            #pragma unroll
            for (int m = 1; m < 64; m <<= 1) ss += __shfl_xor(ss, m);
            float sc = 1.0f / fmaxf(sqrtf(ss), 1e-12f);
            bf2 o; o.x = (__bf16)(v.x * sc); o.y = (__bf16)(v.y * sc);
            reinterpret_cast<bf2*>(Wb + (size_t)row * D_SZ)[lane] = o;
        } else if (row < CPAD) {
            bf2 z; z.x = (__bf16)0.0f; z.y = (__bf16)0.0f;
            reinterpret_cast<bf2*>(Wb + (size_t)row * D_SZ)[lane] = z;
        }
    } else {
        const int i = (b - 25024) * 256 + threadIdx.x;   // 65536 float2
        float2 v = reinterpret_cast<const float2*>(E)[i];
        bf2 o; o.x = (__bf16)v.x; o.y = (__bf16)v.y;
        reinterpret_cast<bf2*>(Eb)[i] = o;
    }
}

// ---- Kernel C: fused GEMM + exp-sum, A in registers, no sA.
// grid = (NG=64, 8 bi), 512 threads (8 waves, 2m x 4n). Per wave: 64 rows x 32 cols.
// LDS: double-buffered sB only (64 KB) -> 2 blocks/CU, 4 waves/SIMD.
__launch_bounds__(512, 4)
__global__ void gemm_lse(const __bf16* __restrict__ Eb, const __bf16* __restrict__ Wb,
                         float* __restrict__ P) {
    __shared__ __bf16 sB[2][BN * D_SZ];   // 2 x 32 KB, XOR-swizzled: byte ^= (row&7)<<4
    __shared__ float  rs[4][BM];          // 2 KB cross-wave reduce

    const int tid  = threadIdx.x;
    const int wave = tid >> 6;
    const int lane = tid & 63;
    const int g4   = lane >> 4;
    const int l15  = lane & 15;
    const int wm   = wave >> 2;           // 0..1 : 64-row slice
    const int wn   = wave & 3;            // 0..3 : 32-col slice
    const int g    = blockIdx.x;          // 0..63
    const int bi   = blockIdx.y;          // 0..7

    const int T = (NCT - g + NG - 1) / NG;   // 13 for g<14, else 12

    const char* wbase = reinterpret_cast<const char*>(Wb);
    // staging source offset (pre-swizzled, pass-invariant part)
    const int srcOff = ((tid >> 4) << 8) + ((((tid & 15) ^ ((tid >> 4) & 7))) << 4);
    const int ldsOff = wave << 10;        // wave-uniform LDS dest base within 8KB pass

    // ---- stage first B tile
    {
        char* sb = reinterpret_cast<char*>(sB[0]);
        #pragma unroll
        for (int j = 0; j < 4; ++j)
            gload_lds16(wbase + (size_t)g * 32768 + j * 8192 + srcOff,
                        sb + j * 8192 + ldsOff);
    }

    // ---- A fragments straight from global (once). 64 rows/wave -> 64 VGPR.
    bf16x8 a[4][4];
    {
        const char* ebase = reinterpret_cast<const char*>(Eb) + (size_t)bi * BM * 256;
        #pragma unroll
        for (int mi = 0; mi < 4; ++mi) {
            const char* pr = ebase + (wm * 64 + mi * 16 + l15) * 256 + g4 * 16;
            #pragma unroll
            for (int kk = 0; kk < 4; ++kk)
                a[mi][kk] = *reinterpret_cast<const bf16x8*>(pr + kk * 64);
        }
    }

    // hoisted ds_read offsets: row = wn*32 + ni*16 + l15 ; byte = (kk*64+g4*16)^((l15&7)<<4)
    const int rowbyte = (wn * 32 + l15) * 256;
    const int swz     = (l15 & 7) << 4;
    int kb[4];
    #pragma unroll
    for (int kk = 0; kk < 4; ++kk) kb[kk] = rowbyte + ((kk * 64 + g4 * 16) ^ swz);

    float rowsum[4][4] = {};   // [mi][r]

    __syncthreads();

    int cur = 0;
    for (int t = 0; t < T; ++t) {
        if (t + 1 < T) {
            const size_t ci = (size_t)(g + (t + 1) * NG) * 32768;
            char* sb = reinterpret_cast<char*>(sB[cur ^ 1]);
            #pragma unroll
            for (int j = 0; j < 4; ++j)
                gload_lds16(wbase + ci + j * 8192 + srcOff, sb + j * 8192 + ldsOff);
        }

        const char* sBb = reinterpret_cast<const char*>(sB[cur]);
        f32x4 acc[4][2] = {};
        #pragma unroll
        for (int kk = 0; kk < 4; ++kk) {
            const char* pb = sBb + kb[kk];
            bf16x8 b0 = *reinterpret_cast<const bf16x8*>(pb);
            bf16x8 b1 = *reinterpret_cast<const bf16x8*>(pb + 4096);
            #pragma unroll
            for (int mi = 0; mi < 4; ++mi) {
                acc[mi][0] = __builtin_amdgcn_mfma_f32_16x16x32_bf16(a[mi][kk], b0, acc[mi][0], 0, 0, 0);
                acc[mi][1] = __builtin_amdgcn_mfma_f32_16x16x32_bf16(a[mi][kk], b1, acc[mi][1], 0, 0, 0);
            }
        }

        // epilogue: rowsum += exp2(min(x*92.33 - 92.33, 0)), raw v_exp_f32
        #pragma unroll
        for (int mi = 0; mi < 4; ++mi) {
            #pragma unroll
            for (int r = 0; r < 4; ++r) {
                float t0 = __builtin_amdgcn_exp2f(fminf(fmaf(acc[mi][0][r], S_LOG2E_F, -S_LOG2E_F), 0.0f));
                float t1 = __builtin_amdgcn_exp2f(fminf(fmaf(acc[mi][1][r], S_LOG2E_F, -S_LOG2E_F), 0.0f));
                rowsum[mi][r] += t0 + t1;
            }
        }
        __syncthreads();   // prefetch landed; cur buffer free
        cur ^= 1;
    }

    // ---- reduce: 16 lanes (l15) in-wave, then 4 wave-cols via LDS
    #pragma unroll
    for (int mi = 0; mi < 4; ++mi) {
        #pragma unroll
        for (int r = 0; r < 4; ++r) {
            float s = rowsum[mi][r];
            s += __shfl_xor(s, 1);
            s += __shfl_xor(s, 2);
            s += __shfl_xor(s, 4);
            s += __shfl_xor(s, 8);
            rowsum[mi][r] = s;
        }
    }
    if (l15 == 0) {
        #pragma unroll
        for (int mi = 0; mi < 4; ++mi)
            #pragma unroll
            for (int r = 0; r < 4; ++r)
                rs[wn][wm * 64 + mi * 16 + g4 * 4 + r] = rowsum[mi][r];
    }
    __syncthreads();
    if (tid < BM)
        P[(size_t)g * B_SZ + bi * BM + tid] = (rs[0][tid] + rs[1][tid]) + (rs[2][tid] + rs[3][tid]);
}

// ---- Kernel D1: per-row S reduce (64 partials) + target dot + nll
__global__ void row_fin(const float* __restrict__ P, const __bf16* __restrict__ Eb,
                        const __bf16* __restrict__ Wb, const int* __restrict__ lab,
                        float* __restrict__ nll) {
    __shared__ float red[256];
    const int row = blockIdx.x;
    const int t   = threadIdx.x;

    red[t] = (t < NG) ? P[(size_t)t * B_SZ + row] : 0.0f;
    __syncthreads();
    #pragma unroll
    for (int off = 128; off > 0; off >>= 1) {
        if (t < off) red[t] += red[t + off];
        __syncthreads();
    }
    const float S = red[0];
    __syncthreads();

    const int lb = lab[row];
    float d = 0.0f;
    if (t < 128) d = (float)Eb[row * D_SZ + t] * (float)Wb[(size_t)lb * D_SZ + t];
    red[t] = d;
    __syncthreads();
    #pragma unroll
    for (int off = 128; off > 0; off >>= 1) {
        if (t < off) red[t] += red[t + off];
        __syncthreads();
    }

    if (t == 0) {
        const float ct = red[0];
        const float cc = fminf(fmaxf(ct, -CLIP_F), CLIP_F);
        const float lt = SCALE_F * (cc - MARGIN_F);
        float Sadj = S - exp2f((SCALE_F * cc - SCALE_F) * LOG2E_F)
                       + exp2f((lt - SCALE_F) * LOG2E_F);
        nll[row] = SCALE_F + logf(Sadj) - lt;
    }
}

// ---- Kernel D2: mean over 1024 rows
__global__ void mean_k(const float* __restrict__ nll, float* __restrict__ out) {
    __shared__ float red[1024];
    const int t = threadIdx.x;
    red[t] = nll[t];
    __syncthreads();
    #pragma unroll
    for (int off = 512; off > 0; off >>= 1) {
        if (t < off) red[t] += red[t + off];
        __syncthreads();
    }
    if (t == 0) out[0] = red[0] * (1.0f / 1024.0f);
}

extern "C" void kernel_launch(void* const* d_in, const int* in_sizes, int n_in,
                              void* d_out, int out_size, void* d_ws, size_t ws_size,
                              hipStream_t stream) {
    const float* E   = (const float*)d_in[0];
    const int*   lab = (const int*)d_in[1];
    const float* W   = (const float*)d_in[2];
    float*       out = (float*)d_out;

    char* ws = (char*)d_ws;
    __bf16* Eb  = (__bf16*)ws;                                   // 262,144 B
    __bf16* Wb  = (__bf16*)(ws + 262144);                        // 25,624,576 B (CPAD rows)
    float*  P   = (float*)(ws + 262144 + 25624576);              // 262,144 B
    float*  nll = (float*)(ws + 262144 + 25624576 + 262144);     // 4,096 B

    norm_conv<<<dim3(25280),   256, 0, stream>>>(W, Wb, E, Eb);
    gemm_lse <<<dim3(NG, 8),   512, 0, stream>>>(Eb, Wb, P);
    row_fin  <<<dim3(B_SZ),    256, 0, stream>>>(P, Eb, Wb, lab, nll);
    mean_k   <<<dim3(1),      1024, 0, stream>>>(nll, out);
}

// Round 4
// 60.873 us; speedup vs baseline: 1.1878x; 1.1878x over previous
//
#include <hip/hip_runtime.h>
#include <hip/hip_bf16.h>

typedef __bf16 bf16x8 __attribute__((ext_vector_type(8)));
typedef float  f32x4  __attribute__((ext_vector_type(4)));

#define B_SZ 1024
#define D_SZ 128
#define C_SZ 100000
#define CPAD 100096          // padded class rows (zero tail), 782*128
#define BM 128
#define BN 128
#define NG 64                // C-tile groups (grid.x)
#define NCT 782              // ceil(100000/128)

#define SCALE_F   64.0f
#define MARGIN_F  0.35f
#define CLIP_F    (1.0f - 1e-7f)
#define LOG2E_F   1.4426950408889634f
#define S_LOG2E_F (64.0f * 1.4426950408889634f)

struct bf2 { __bf16 x, y; };

__device__ __forceinline__ void gload_lds16(const void* g, void* l) {
    __builtin_amdgcn_global_load_lds(
        (const __attribute__((address_space(1))) void*)g,
        (__attribute__((address_space(3))) void*)l, 16, 0, 0);
}

// ---- Kernel A: L2-normalize W rows -> bf16 (+zero pad rows) + convert E -> bf16
__global__ void norm_conv(const float* __restrict__ W, __bf16* __restrict__ Wb,
                          const float* __restrict__ E, __bf16* __restrict__ Eb) {
    const int b = blockIdx.x;
    if (b < 25024) {
        const int row  = b * 4 + (threadIdx.x >> 6);
        const int lane = threadIdx.x & 63;
        if (row < C_SZ) {
            float2 v = reinterpret_cast<const float2*>(W + (size_t)row * D_SZ)[lane];
            float ss = v.x * v.x + v.y * v.y;
            #pragma unroll
            for (int m = 1; m < 64; m <<= 1) ss += __shfl_xor(ss, m);
            float sc = 1.0f / fmaxf(sqrtf(ss), 1e-12f);
            bf2 o; o.x = (__bf16)(v.x * sc); o.y = (__bf16)(v.y * sc);
            reinterpret_cast<bf2*>(Wb + (size_t)row * D_SZ)[lane] = o;
        } else if (row < CPAD) {
            bf2 z; z.x = (__bf16)0.0f; z.y = (__bf16)0.0f;
            reinterpret_cast<bf2*>(Wb + (size_t)row * D_SZ)[lane] = z;
        }
    } else {
        const int i = (b - 25024) * 256 + threadIdx.x;   // 65536 float2
        float2 v = reinterpret_cast<const float2*>(E)[i];
        bf2 o; o.x = (__bf16)v.x; o.y = (__bf16)v.y;
        reinterpret_cast<bf2*>(Eb)[i] = o;
    }
}

// ---- Kernel C: fused GEMM + exp-sum, A in registers, no sA.
// grid = (NG=64, 8 bi), 512 threads (8 waves, 4m x 2n). Per wave: 32 rows x 64 cols.
// VGPR budget: a[2][4]=32, acc[2][4]=32, rowsum=8, addr/misc ~30 -> ~105, no spill.
// LDS: double-buffered sB (64 KB) + 1 KB -> 2 blocks/CU.
__launch_bounds__(512, 3)
__global__ void gemm_lse(const __bf16* __restrict__ Eb, const __bf16* __restrict__ Wb,
                         float* __restrict__ P) {
    __shared__ __bf16 sB[2][BN * D_SZ];   // 2 x 32 KB, XOR-swizzled: byte ^= (row&7)<<4
    __shared__ float  rs[2][BM];          // 1 KB cross-wave reduce

    const int tid  = threadIdx.x;
    const int wave = tid >> 6;
    const int lane = tid & 63;
    const int g4   = lane >> 4;
    const int l15  = lane & 15;
    const int wm   = wave >> 1;           // 0..3 : 32-row slice
    const int wn   = wave & 1;            // 0..1 : 64-col slice
    const int g    = blockIdx.x;          // 0..63
    const int bi   = blockIdx.y;          // 0..7

    const int T = (NCT - g + NG - 1) / NG;   // 13 for g<14, else 12

    const char* wbase = reinterpret_cast<const char*>(Wb);
    // staging source offset (pre-swizzled, pass-invariant part)
    const int srcOff = ((tid >> 4) << 8) + ((((tid & 15) ^ ((tid >> 4) & 7))) << 4);
    const int ldsOff = wave << 10;        // wave-uniform LDS dest base within 8KB pass

    // ---- stage first B tile
    {
        char* sb = reinterpret_cast<char*>(sB[0]);
        #pragma unroll
        for (int j = 0; j < 4; ++j)
            gload_lds16(wbase + (size_t)g * 32768 + j * 8192 + srcOff,
                        sb + j * 8192 + ldsOff);
    }

    // ---- A fragments straight from global (once). 32 rows/wave -> 32 VGPR.
    bf16x8 a[2][4];
    {
        const char* ebase = reinterpret_cast<const char*>(Eb) + (size_t)bi * BM * 256;
        #pragma unroll
        for (int mi = 0; mi < 2; ++mi) {
            const char* pr = ebase + (wm * 32 + mi * 16 + l15) * 256 + g4 * 16;
            #pragma unroll
            for (int kk = 0; kk < 4; ++kk)
                a[mi][kk] = *reinterpret_cast<const bf16x8*>(pr + kk * 64);
        }
    }

    // hoisted ds_read offsets: row = wn*64 + ni*16 + l15 ; byte = (kk*64+g4*16)^((l15&7)<<4)
    const int swz = (l15 & 7) << 4;
    int rowb[4];
    #pragma unroll
    for (int ni = 0; ni < 4; ++ni) rowb[ni] = (wn * 64 + ni * 16 + l15) * 256;
    int kb[4];
    #pragma unroll
    for (int kk = 0; kk < 4; ++kk) kb[kk] = (kk * 64 + g4 * 16) ^ swz;

    float rowsum[2][4] = {};   // [mi][r]

    __syncthreads();

    int cur = 0;
    for (int t = 0; t < T; ++t) {
        if (t + 1 < T) {
            const size_t ci = (size_t)(g + (t + 1) * NG) * 32768;
            char* sb = reinterpret_cast<char*>(sB[cur ^ 1]);
            #pragma unroll
            for (int j = 0; j < 4; ++j)
                gload_lds16(wbase + ci + j * 8192 + srcOff, sb + j * 8192 + ldsOff);
        }

        const char* sBb = reinterpret_cast<const char*>(sB[cur]);
        f32x4 acc[2][4] = {};
        #pragma unroll
        for (int kk = 0; kk < 4; ++kk) {
            bf16x8 b[4];
            #pragma unroll
            for (int ni = 0; ni < 4; ++ni)
                b[ni] = *reinterpret_cast<const bf16x8*>(sBb + rowb[ni] + kb[kk]);
            #pragma unroll
            for (int mi = 0; mi < 2; ++mi)
                #pragma unroll
                for (int ni = 0; ni < 4; ++ni)
                    acc[mi][ni] = __builtin_amdgcn_mfma_f32_16x16x32_bf16(
                        a[mi][kk], b[ni], acc[mi][ni], 0, 0, 0);
        }

        // epilogue: rowsum += exp2(min(x*92.33 - 92.33, 0)), raw v_exp_f32
        #pragma unroll
        for (int mi = 0; mi < 2; ++mi) {
            #pragma unroll
            for (int r = 0; r < 4; ++r) {
                float s0 = 0.0f;
                #pragma unroll
                for (int ni = 0; ni < 4; ++ni)
                    s0 += __builtin_amdgcn_exp2f(
                        fminf(fmaf(acc[mi][ni][r], S_LOG2E_F, -S_LOG2E_F), 0.0f));
                rowsum[mi][r] += s0;
            }
        }
        __syncthreads();   // prefetch landed; cur buffer free
        cur ^= 1;
    }

    // ---- reduce: 16 lanes (l15) in-wave, then 2 wave-cols via LDS
    #pragma unroll
    for (int mi = 0; mi < 2; ++mi) {
        #pragma unroll
        for (int r = 0; r < 4; ++r) {
            float s = rowsum[mi][r];
            s += __shfl_xor(s, 1);
            s += __shfl_xor(s, 2);
            s += __shfl_xor(s, 4);
            s += __shfl_xor(s, 8);
            rowsum[mi][r] = s;
        }
    }
    if (l15 == 0) {
        #pragma unroll
        for (int mi = 0; mi < 2; ++mi)
            #pragma unroll
            for (int r = 0; r < 4; ++r)
                rs[wn][wm * 32 + mi * 16 + g4 * 4 + r] = rowsum[mi][r];
    }
    __syncthreads();
    if (tid < BM)
        P[(size_t)g * B_SZ + bi * BM + tid] = rs[0][tid] + rs[1][tid];
}

// ---- Kernel D1: per-row S reduce (64 partials) + target dot + nll
__global__ void row_fin(const float* __restrict__ P, const __bf16* __restrict__ Eb,
                        const __bf16* __restrict__ Wb, const int* __restrict__ lab,
                        float* __restrict__ nll) {
    __shared__ float red[256];
    const int row = blockIdx.x;
    const int t   = threadIdx.x;

    red[t] = (t < NG) ? P[(size_t)t * B_SZ + row] : 0.0f;
    __syncthreads();
    #pragma unroll
    for (int off = 128; off > 0; off >>= 1) {
        if (t < off) red[t] += red[t + off];
        __syncthreads();
    }
    const float S = red[0];
    __syncthreads();

    const int lb = lab[row];
    float d = 0.0f;
    if (t < 128) d = (float)Eb[row * D_SZ + t] * (float)Wb[(size_t)lb * D_SZ + t];
    red[t] = d;
    __syncthreads();
    #pragma unroll
    for (int off = 128; off > 0; off >>= 1) {
        if (t < off) red[t] += red[t + off];
        __syncthreads();
    }

    if (t == 0) {
        const float ct = red[0];
        const float cc = fminf(fmaxf(ct, -CLIP_F), CLIP_F);
        const float lt = SCALE_F * (cc - MARGIN_F);
        float Sadj = S - exp2f((SCALE_F * cc - SCALE_F) * LOG2E_F)
                       + exp2f((lt - SCALE_F) * LOG2E_F);
        nll[row] = SCALE_F + logf(Sadj) - lt;
    }
}

// ---- Kernel D2: mean over 1024 rows
__global__ void mean_k(const float* __restrict__ nll, float* __restrict__ out) {
    __shared__ float red[1024];
    const int t = threadIdx.x;
    red[t] = nll[t];
    __syncthreads();
    #pragma unroll
    for (int off = 512; off > 0; off >>= 1) {
        if (t < off) red[t] += red[t + off];
        __syncthreads();
    }
    if (t == 0) out[0] = red[0] * (1.0f / 1024.0f);
}

extern "C" void kernel_launch(void* const* d_in, const int* in_sizes, int n_in,
                              void* d_out, int out_size, void* d_ws, size_t ws_size,
                              hipStream_t stream) {
    const float* E   = (const float*)d_in[0];
    const int*   lab = (const int*)d_in[1];
    const float* W   = (const float*)d_in[2];
    float*       out = (float*)d_out;

    char* ws = (char*)d_ws;
    __bf16* Eb  = (__bf16*)ws;                                   // 262,144 B
    __bf16* Wb  = (__bf16*)(ws + 262144);                        // 25,624,576 B (CPAD rows)
    float*  P   = (float*)(ws + 262144 + 25624576);              // 262,144 B
    float*  nll = (float*)(ws + 262144 + 25624576 + 262144);     // 4,096 B

    norm_conv<<<dim3(25280),   256, 0, stream>>>(W, Wb, E, Eb);
    gemm_lse <<<dim3(NG, 8),   512, 0, stream>>>(Eb, Wb, P);
    row_fin  <<<dim3(B_SZ),    256, 0, stream>>>(P, Eb, Wb, lab, nll);
    mean_k   <<<dim3(1),      1024, 0, stream>>>(nll, out);
}

// Round 5
// 56.857 us; speedup vs baseline: 1.2717x; 1.0706x over previous
//
#include <hip/hip_runtime.h>
#include <hip/hip_bf16.h>

typedef __bf16 bf16x8 __attribute__((ext_vector_type(8)));
typedef float  f32x4  __attribute__((ext_vector_type(4)));

#define B_SZ 1024
#define D_SZ 128
#define C_SZ 100000
#define CPAD 100096          // padded class rows (zero tail), 782*128
#define BM 128
#define BN 128
#define NG 64                // C-tile groups (grid.x)
#define NCT 782              // ceil(100000/128)

#define SCALE_F   64.0f
#define MARGIN_F  0.35f
#define CLIP_F    (1.0f - 1e-7f)
#define LOG2E_F   1.4426950408889634f
#define S_LOG2E_F (64.0f * 1.4426950408889634f)

__device__ __forceinline__ void gload_lds16(const void* g, void* l) {
    __builtin_amdgcn_global_load_lds(
        (const __attribute__((address_space(1))) void*)g,
        (__attribute__((address_space(3))) void*)l, 16, 0, 0);
}

// ---- Kernel A: L2-normalize W rows -> bf16 (+zero pad) + convert E -> bf16.
// float4 per lane, 2 rows per wave, 8 rows per 256-thr block.
__global__ void norm_conv(const float* __restrict__ W, __bf16* __restrict__ Wb,
                          const float* __restrict__ E, __bf16* __restrict__ Eb) {
    const int b = blockIdx.x;
    if (b < 12512) {
        const int lane = threadIdx.x & 63;
        const int l32  = lane & 31;
        const int row  = b * 8 + ((threadIdx.x >> 6) << 1) + (lane >> 5);
        if (row < C_SZ) {
            float4 v = reinterpret_cast<const float4*>(W + (size_t)row * D_SZ)[l32];
            float ss = v.x * v.x + v.y * v.y + v.z * v.z + v.w * v.w;
            #pragma unroll
            for (int m = 1; m < 32; m <<= 1) ss += __shfl_xor(ss, m);
            float sc = 1.0f / fmaxf(sqrtf(ss), 1e-12f);
            union { __bf16 h[4]; uint2 u; } o;
            o.h[0] = (__bf16)(v.x * sc); o.h[1] = (__bf16)(v.y * sc);
            o.h[2] = (__bf16)(v.z * sc); o.h[3] = (__bf16)(v.w * sc);
            reinterpret_cast<uint2*>(Wb + (size_t)row * D_SZ)[l32] = o.u;
        } else {   // zero pad rows [C_SZ, CPAD)
            uint2 z; z.x = 0u; z.y = 0u;
            reinterpret_cast<uint2*>(Wb + (size_t)row * D_SZ)[l32] = z;
        }
    } else {
        const int i = (b - 12512) * 256 + threadIdx.x;   // 32768 float4
        float4 v = reinterpret_cast<const float4*>(E)[i];
        union { __bf16 h[4]; uint2 u; } o;
        o.h[0] = (__bf16)v.x; o.h[1] = (__bf16)v.y;
        o.h[2] = (__bf16)v.z; o.h[3] = (__bf16)v.w;
        reinterpret_cast<uint2*>(Eb)[i] = o.u;
    }
}

// ---- Kernel C: fused GEMM + exp-sum; A in regs; half-tile pipelined epilogue.
// grid = (NG=64, 8 bi), 512 threads (8 waves, 4m x 2n). Per wave: 32 rows x 64 cols.
// acc split acA(ni0-1)/acB(ni2-3): EPI(prev half) overlaps next half's MFMAs.
__launch_bounds__(512, 3)
__global__ void gemm_lse(const __bf16* __restrict__ Eb, const __bf16* __restrict__ Wb,
                         float* __restrict__ P) {
    __shared__ __bf16 sB[2][BN * D_SZ];   // 2 x 32 KB, XOR-swizzled: byte ^= (row&7)<<4
    __shared__ float  rs[2][BM];          // 1 KB cross-wave reduce

    const int tid  = threadIdx.x;
    const int wave = tid >> 6;
    const int lane = tid & 63;
    const int g4   = lane >> 4;
    const int l15  = lane & 15;
    const int wm   = wave >> 1;           // 0..3 : 32-row slice
    const int wn   = wave & 1;            // 0..1 : 64-col slice
    const int g    = blockIdx.x;          // 0..63
    const int bi   = blockIdx.y;          // 0..7

    const int T = (NCT - g + NG - 1) / NG;   // 13 for g<14, else 12

    const char* wbase = reinterpret_cast<const char*>(Wb);
    const int srcOff = ((tid >> 4) << 8) + ((((tid & 15) ^ ((tid >> 4) & 7))) << 4);
    const int ldsOff = wave << 10;

    // ---- stage first B tile
    {
        char* sb = reinterpret_cast<char*>(sB[0]);
        #pragma unroll
        for (int j = 0; j < 4; ++j)
            gload_lds16(wbase + (size_t)g * 32768 + j * 8192 + srcOff,
                        sb + j * 8192 + ldsOff);
    }

    // ---- A fragments straight from global (once). 32 rows/wave -> 32 VGPR.
    bf16x8 a[2][4];
    {
        const char* ebase = reinterpret_cast<const char*>(Eb) + (size_t)bi * BM * 256;
        #pragma unroll
        for (int mi = 0; mi < 2; ++mi) {
            const char* pr = ebase + (wm * 32 + mi * 16 + l15) * 256 + g4 * 16;
            #pragma unroll
            for (int kk = 0; kk < 4; ++kk)
                a[mi][kk] = *reinterpret_cast<const bf16x8*>(pr + kk * 64);
        }
    }

    // hoisted ds_read offsets: row = wn*64 + ni*16 + l15 ; byte = (kk*64+g4*16)^((l15&7)<<4)
    const int swz = (l15 & 7) << 4;
    int rowb[4];
    #pragma unroll
    for (int ni = 0; ni < 4; ++ni) rowb[ni] = (wn * 64 + ni * 16 + l15) * 256;
    int kb[4];
    #pragma unroll
    for (int kk = 0; kk < 4; ++kk) kb[kk] = (kk * 64 + g4 * 16) ^ swz;

    float rowsum[2][4] = {};   // [mi][r]

#define EPI(AC)                                                                  \
    _Pragma("unroll")                                                            \
    for (int mi = 0; mi < 2; ++mi) {                                             \
        _Pragma("unroll")                                                        \
        for (int r = 0; r < 4; ++r) {                                            \
            rowsum[mi][r] += __builtin_amdgcn_exp2f(                             \
                fminf(fmaf(AC[mi][0][r], S_LOG2E_F, -S_LOG2E_F), 0.0f));         \
            rowsum[mi][r] += __builtin_amdgcn_exp2f(                             \
                fminf(fmaf(AC[mi][1][r], S_LOG2E_F, -S_LOG2E_F), 0.0f));         \
        }                                                                        \
    }

    f32x4 acA[2][2], acB[2][2];
    #pragma unroll
    for (int mi = 0; mi < 2; ++mi)
        #pragma unroll
        for (int nh = 0; nh < 2; ++nh)
            acB[mi][nh] = (f32x4){0.f, 0.f, 0.f, 0.f};   // pre-loop EPI(acB) adds ~2^-92 ~ 0

    __syncthreads();

    int cur = 0;
    for (int t = 0; t < T; ++t) {
        if (t + 1 < T) {
            const size_t ci = (size_t)(g + (t + 1) * NG) * 32768;
            char* sb = reinterpret_cast<char*>(sB[cur ^ 1]);
            #pragma unroll
            for (int j = 0; j < 4; ++j)
                gload_lds16(wbase + ci + j * 8192 + srcOff, sb + j * 8192 + ldsOff);
        }

        const char* sBb = reinterpret_cast<const char*>(sB[cur]);

        // ---- half 0: ni = 0,1 -> acA
        __builtin_amdgcn_s_setprio(1);
        #pragma unroll
        for (int mi = 0; mi < 2; ++mi)
            #pragma unroll
            for (int nh = 0; nh < 2; ++nh)
                acA[mi][nh] = (f32x4){0.f, 0.f, 0.f, 0.f};
        #pragma unroll
        for (int kk = 0; kk < 4; ++kk) {
            bf16x8 b0 = *reinterpret_cast<const bf16x8*>(sBb + rowb[0] + kb[kk]);
            bf16x8 b1 = *reinterpret_cast<const bf16x8*>(sBb + rowb[1] + kb[kk]);
            acA[0][0] = __builtin_amdgcn_mfma_f32_16x16x32_bf16(a[0][kk], b0, acA[0][0], 0, 0, 0);
            acA[1][0] = __builtin_amdgcn_mfma_f32_16x16x32_bf16(a[1][kk], b0, acA[1][0], 0, 0, 0);
            acA[0][1] = __builtin_amdgcn_mfma_f32_16x16x32_bf16(a[0][kk], b1, acA[0][1], 0, 0, 0);
            acA[1][1] = __builtin_amdgcn_mfma_f32_16x16x32_bf16(a[1][kk], b1, acA[1][1], 0, 0, 0);
        }
        __builtin_amdgcn_s_setprio(0);
        EPI(acB);   // previous tile's second half overlaps H0's MFMA drain

        // ---- half 1: ni = 2,3 -> acB
        __builtin_amdgcn_s_setprio(1);
        #pragma unroll
        for (int mi = 0; mi < 2; ++mi)
            #pragma unroll
            for (int nh = 0; nh < 2; ++nh)
                acB[mi][nh] = (f32x4){0.f, 0.f, 0.f, 0.f};
        #pragma unroll
        for (int kk = 0; kk < 4; ++kk) {
            bf16x8 b2 = *reinterpret_cast<const bf16x8*>(sBb + rowb[2] + kb[kk]);
            bf16x8 b3 = *reinterpret_cast<const bf16x8*>(sBb + rowb[3] + kb[kk]);
            acB[0][0] = __builtin_amdgcn_mfma_f32_16x16x32_bf16(a[0][kk], b2, acB[0][0], 0, 0, 0);
            acB[1][0] = __builtin_amdgcn_mfma_f32_16x16x32_bf16(a[1][kk], b2, acB[1][0], 0, 0, 0);
            acB[0][1] = __builtin_amdgcn_mfma_f32_16x16x32_bf16(a[0][kk], b3, acB[0][1], 0, 0, 0);
            acB[1][1] = __builtin_amdgcn_mfma_f32_16x16x32_bf16(a[1][kk], b3, acB[1][1], 0, 0, 0);
        }
        __builtin_amdgcn_s_setprio(0);
        EPI(acA);   // this tile's first half overlaps H1's MFMA drain

        __syncthreads();   // prefetch landed; cur buffer free
        cur ^= 1;
    }
    EPI(acB);   // final tile's second half

    // ---- reduce: 16 lanes (l15) in-wave, then 2 wave-cols via LDS
    #pragma unroll
    for (int mi = 0; mi < 2; ++mi) {
        #pragma unroll
        for (int r = 0; r < 4; ++r) {
            float s = rowsum[mi][r];
            s += __shfl_xor(s, 1);
            s += __shfl_xor(s, 2);
            s += __shfl_xor(s, 4);
            s += __shfl_xor(s, 8);
            rowsum[mi][r] = s;
        }
    }
    if (l15 == 0) {
        #pragma unroll
        for (int mi = 0; mi < 2; ++mi)
            #pragma unroll
            for (int r = 0; r < 4; ++r)
                rs[wn][wm * 32 + mi * 16 + g4 * 4 + r] = rowsum[mi][r];
    }
    __syncthreads();
    if (tid < BM)
        P[(size_t)g * B_SZ + bi * BM + tid] = rs[0][tid] + rs[1][tid];
}

// ---- Kernel D1: per-row S reduce (64 partials) + target dot + nll
__global__ void row_fin(const float* __restrict__ P, const __bf16* __restrict__ Eb,
                        const __bf16* __restrict__ Wb, const int* __restrict__ lab,
                        float* __restrict__ nll) {
    __shared__ float red[256];
    const int row = blockIdx.x;
    const int t   = threadIdx.x;

    red[t] = (t < NG) ? P[(size_t)t * B_SZ + row] : 0.0f;
    __syncthreads();
    #pragma unroll
    for (int off = 128; off > 0; off >>= 1) {
        if (t < off) red[t] += red[t + off];
        __syncthreads();
    }
    const float S = red[0];
    __syncthreads();

    const int lb = lab[row];
    float d = 0.0f;
    if (t < 128) d = (float)Eb[row * D_SZ + t] * (float)Wb[(size_t)lb * D_SZ + t];
    red[t] = d;
    __syncthreads();
    #pragma unroll
    for (int off = 128; off > 0; off >>= 1) {
        if (t < off) red[t] += red[t + off];
        __syncthreads();
    }

    if (t == 0) {
        const float ct = red[0];
        const float cc = fminf(fmaxf(ct, -CLIP_F), CLIP_F);
        const float lt = SCALE_F * (cc - MARGIN_F);
        float Sadj = S - exp2f((SCALE_F * cc - SCALE_F) * LOG2E_F)
                       + exp2f((lt - SCALE_F) * LOG2E_F);
        nll[row] = SCALE_F + logf(Sadj) - lt;
    }
}

// ---- Kernel D2: mean over 1024 rows (shuffle-based)
__global__ void mean_k(const float* __restrict__ nll, float* __restrict__ out) {
    __shared__ float part[16];
    const int t = threadIdx.x;
    float v = nll[t];
    #pragma unroll
    for (int m = 1; m < 64; m <<= 1) v += __shfl_xor(v, m);
    if ((t & 63) == 0) part[t >> 6] = v;
    __syncthreads();
    if (t < 16) {
        float u = part[t];
        #pragma unroll
        for (int m = 1; m < 16; m <<= 1) u += __shfl_xor(u, m);
        if (t == 0) out[0] = u * (1.0f / 1024.0f);
    }
}

extern "C" void kernel_launch(void* const* d_in, const int* in_sizes, int n_in,
                              void* d_out, int out_size, void* d_ws, size_t ws_size,
                              hipStream_t stream) {
    const float* E   = (const float*)d_in[0];
    const int*   lab = (const int*)d_in[1];
    const float* W   = (const float*)d_in[2];
    float*       out = (float*)d_out;

    char* ws = (char*)d_ws;
    __bf16* Eb  = (__bf16*)ws;                                   // 262,144 B
    __bf16* Wb  = (__bf16*)(ws + 262144);                        // 25,624,576 B (CPAD rows)
    float*  P   = (float*)(ws + 262144 + 25624576);              // 262,144 B
    float*  nll = (float*)(ws + 262144 + 25624576 + 262144);     // 4,096 B

    norm_conv<<<dim3(12640),   256, 0, stream>>>(W, Wb, E, Eb);
    gemm_lse <<<dim3(NG, 8),   512, 0, stream>>>(Eb, Wb, P);
    row_fin  <<<dim3(B_SZ),    256, 0, stream>>>(P, Eb, Wb, lab, nll);
    mean_k   <<<dim3(1),      1024, 0, stream>>>(nll, out);
}